// Round 5
// baseline (3490.093 us; speedup 1.0000x reference)
//
#include <hip/hip_runtime.h>
#include <cstdint>
#include <cstddef>

#define N_NODES 100000
#define M_EDGES 20000
#define P_PAIRS 1600000
#define CIN 768
#define HID 128
#define OUT_C 16
#define NLAYERS 16
#define LN_EPS 1e-5f
#define NCHUNK 4
#define CW 32            // chunk width in cols (== bytes, fp8)

using half8  = __attribute__((ext_vector_type(8))) _Float16;
using half4v = __attribute__((ext_vector_type(4))) _Float16;
using half2v = __attribute__((ext_vector_type(2))) _Float16;
using f32x4  = __attribute__((ext_vector_type(4))) float;
using f32x2  = __attribute__((ext_vector_type(2))) float;
using u32x4  = __attribute__((ext_vector_type(4))) unsigned int;

#if defined(__has_builtin)
#if __has_builtin(__builtin_amdgcn_cvt_pk_f32_fp8) && __has_builtin(__builtin_amdgcn_cvt_pk_fp8_f32)
#define HAVE_HW_FP8 1
#endif
#endif

#ifndef HAVE_HW_FP8
#include <hip/hip_fp8.h>
#endif

// ---- fp8 e4m3 helpers ----

__device__ __forceinline__ void acc4w(float* acc, unsigned w) {
#ifdef HAVE_HW_FP8
    f32x2 lo = __builtin_amdgcn_cvt_pk_f32_fp8((int)w, false);
    f32x2 hi = __builtin_amdgcn_cvt_pk_f32_fp8((int)w, true);
    acc[0] += lo[0]; acc[1] += lo[1]; acc[2] += hi[0]; acc[3] += hi[1];
#else
#pragma unroll
    for (int i = 0; i < 4; i++) {
        __half_raw hr = __hip_cvt_fp8_to_halfraw((__hip_fp8_storage_t)((w >> (8 * i)) & 0xffu), __HIP_E4M3);
        acc[i] += __half2float(*(__half*)&hr);
    }
#endif
}

__device__ __forceinline__ void acc16v(float* acc, u32x4 w) {
    acc4w(acc + 0,  w[0]);
    acc4w(acc + 4,  w[1]);
    acc4w(acc + 8,  w[2]);
    acc4w(acc + 12, w[3]);
}

__device__ __forceinline__ unsigned char f32_to_fp8(float v) {
#ifdef HAVE_HW_FP8
    return (unsigned char)(__builtin_amdgcn_cvt_pk_fp8_f32(v, v, 0, false) & 0xff);
#else
    return (unsigned char)__hip_cvt_float_to_fp8(v, __HIP_SATFINITE, __HIP_E4M3);
#endif
}

__device__ __forceinline__ unsigned short pack2_fp8(float a, float b) {
#ifdef HAVE_HW_FP8
    return (unsigned short)(__builtin_amdgcn_cvt_pk_fp8_f32(a, b, 0, false) & 0xffff);
#else
    return (unsigned short)((unsigned)f32_to_fp8(a) | ((unsigned)f32_to_fp8(b) << 8));
#endif
}

__device__ __forceinline__ unsigned pack4_fp8(float a, float b, float c, float d) {
#ifdef HAVE_HW_FP8
    int w = __builtin_amdgcn_cvt_pk_fp8_f32(a, b, 0, false);
    w = __builtin_amdgcn_cvt_pk_fp8_f32(c, d, w, true);
    return (unsigned)w;
#else
    return (unsigned)f32_to_fp8(a) | ((unsigned)f32_to_fp8(b) << 8) |
           ((unsigned)f32_to_fp8(c) << 16) | ((unsigned)f32_to_fp8(d) << 24);
#endif
}

// ------------------------- CSR build -------------------------

__global__ void hist_kernel(const int* __restrict__ v_idx, const int* __restrict__ e_idx,
                            unsigned* __restrict__ cnt_v, unsigned* __restrict__ cnt_e) {
    int p = blockIdx.x * 256 + threadIdx.x;
    if (p < P_PAIRS) {
        atomicAdd(&cnt_v[v_idx[p]], 1u);
        atomicAdd(&cnt_e[e_idx[p]], 1u);
    }
}

// ---- parallel scan: 3 phases ----
#define SCAN_EPT 16
#define SCAN_CHUNK 4096   // 256 threads * 16

__global__ void scan_block_sums(const unsigned* __restrict__ cnt, int n,
                                unsigned* __restrict__ bsum) {
    __shared__ unsigned ws[4];
    int t = threadIdx.x;
    int base = blockIdx.x * SCAN_CHUNK + t * SCAN_EPT;
    unsigned s = 0;
#pragma unroll
    for (int i = 0; i < SCAN_EPT; i++) {
        int idx = base + i;
        if (idx < n) s += cnt[idx];
    }
#pragma unroll
    for (int off = 1; off < 64; off <<= 1) s += __shfl_xor(s, off);
    int lane = t & 63, w = t >> 6;
    if (lane == 0) ws[w] = s;
    __syncthreads();
    if (t == 0) bsum[blockIdx.x] = ws[0] + ws[1] + ws[2] + ws[3];
}

// single wave; B <= 64
__global__ void scan_tops(const unsigned* __restrict__ bsum, int B,
                          unsigned* __restrict__ bbase, unsigned* __restrict__ total_out) {
    int t = threadIdx.x;
    unsigned v = (t < B) ? bsum[t] : 0u;
    unsigned s = v;
#pragma unroll
    for (int off = 1; off < 64; off <<= 1) {
        unsigned u = __shfl_up(s, off);
        if (t >= off) s += u;
    }
    if (t < B) bbase[t] = s - v;
    if (t == 63) *total_out = s;
}

__global__ void scan_final(const unsigned* __restrict__ cnt, int n,
                           const unsigned* __restrict__ bbase,
                           unsigned* __restrict__ offs, unsigned* __restrict__ cur,
                           float* __restrict__ inv) {
    __shared__ unsigned wtot[4];
    int t = threadIdx.x;
    int lane = t & 63, w = t >> 6;
    int base = blockIdx.x * SCAN_CHUNK + t * SCAN_EPT;
    unsigned vals[SCAN_EPT];
    unsigned tsum = 0;
#pragma unroll
    for (int i = 0; i < SCAN_EPT; i++) {
        int idx = base + i;
        unsigned v = (idx < n) ? cnt[idx] : 0u;
        vals[i] = v;
        tsum += v;
    }
    unsigned s = tsum;
#pragma unroll
    for (int off = 1; off < 64; off <<= 1) {
        unsigned u = __shfl_up(s, off);
        if (lane >= off) s += u;
    }
    unsigned texcl = s - tsum;
    if (lane == 63) wtot[w] = s;
    __syncthreads();
    unsigned wbase = 0;
    for (int i = 0; i < w; i++) wbase += wtot[i];
    unsigned run = bbase[blockIdx.x] + wbase + texcl;
#pragma unroll
    for (int i = 0; i < SCAN_EPT; i++) {
        int idx = base + i;
        if (idx < n) {
            offs[idx] = run;
            cur[idx] = run;
            unsigned c = vals[i];
            inv[idx] = 1.0f / (float)(c > 1u ? c : 1u);
            run += c;
        }
    }
}

// ---- fills: separate kernels (merged variant measured pathological: 280us, 6.8GB FETCH) ----

__global__ void fill_v_kernel(const int* __restrict__ v_idx, const int* __restrict__ e_idx,
                              unsigned* __restrict__ cur_v, unsigned short* __restrict__ vert_nbr) {
    int p = blockIdx.x * 256 + threadIdx.x;
    if (p < P_PAIRS) {
        unsigned s = atomicAdd(&cur_v[v_idx[p]], 1u);
        vert_nbr[s] = (unsigned short)e_idx[p];   // e < 20000 fits u16
    }
}

__global__ void fill_e_kernel(const int* __restrict__ v_idx, const int* __restrict__ e_idx,
                              unsigned* __restrict__ cur_e, int* __restrict__ edge_nbr) {
    int p = blockIdx.x * 256 + threadIdx.x;
    if (p < P_PAIRS) {
        unsigned s = atomicAdd(&cur_e[e_idx[p]], 1u);
        edge_nbr[s] = v_idx[p];
    }
}

// ------------------------- weight transpose+convert -------------------------

__global__ void convert_wT_kernel(const float* __restrict__ W, _Float16* __restrict__ WT,
                                  int K) {
    const float* src = W + (size_t)blockIdx.y * K * 128;
    _Float16* dst = WT + (size_t)blockIdx.y * K * 128;
    int idx = blockIdx.x * 256 + threadIdx.x;
    if (idx < K * 128) {
        int k = idx >> 7, n = idx & 127;
        dst[(size_t)n * K + k] = (_Float16)src[idx];
    }
}

// ------------------------- MFMA GEMM -------------------------

#define BK  64
#define LDK 72

// OMODE 0: f32 row-major out (encoder -> x)
// OMODE 1: fp8 row-major out (theta -> Xe8[nrows][128])
template<bool A_FP32, int OMODE>
__global__ __launch_bounds__(256) void mfma_gemm_kernel(
    const void* __restrict__ Ap, const _Float16* __restrict__ Bt,
    const float* __restrict__ bias, void* __restrict__ outp,
    int nrows, int K) {
    __shared__ _Float16 Asm[128 * LDK];
    __shared__ _Float16 Bsm[128 * LDK];
    int tid = threadIdx.x;
    int row0 = blockIdx.x * 128;
    int lane = tid & 63, wave = tid >> 6;
    int wy = wave >> 1, wx = wave & 1;
    int m16 = lane & 15, quad = lane >> 4;

    f32x4 acc[4][4];
#pragma unroll
    for (int r = 0; r < 4; r++)
#pragma unroll
        for (int c = 0; c < 4; c++) acc[r][c] = (f32x4)0.f;

    float bv[4];
#pragma unroll
    for (int c = 0; c < 4; c++) bv[c] = bias[wx * 64 + c * 16 + m16];

    for (int k0 = 0; k0 < K; k0 += BK) {
        __syncthreads();
        if (A_FP32) {
            const float* A = (const float*)Ap;
#pragma unroll
            for (int i = 0; i < 8; i++) {
                int idx = tid + i * 256;
                int r = idx >> 4, c = idx & 15;
                int rg = row0 + r; if (rg >= nrows) rg = nrows - 1;
                float4 v = *(const float4*)(A + (size_t)rg * K + k0 + c * 4);
                half4v h = { (_Float16)v.x, (_Float16)v.y, (_Float16)v.z, (_Float16)v.w };
                *(half4v*)&Asm[r * LDK + c * 4] = h;
            }
        } else {
            const _Float16* A = (const _Float16*)Ap;
#pragma unroll
            for (int i = 0; i < 4; i++) {
                int idx = tid + i * 256;
                int r = idx >> 3, c = idx & 7;
                int rg = row0 + r; if (rg >= nrows) rg = nrows - 1;
                half8 v = *(const half8*)(A + (size_t)rg * K + k0 + c * 8);
                *(half8*)&Asm[r * LDK + c * 8] = v;
            }
        }
#pragma unroll
        for (int i = 0; i < 4; i++) {
            int idx = tid + i * 256;
            int r = idx >> 3, c = idx & 7;
            half8 v = *(const half8*)(Bt + (size_t)r * K + k0 + c * 8);
            *(half8*)&Bsm[r * LDK + c * 8] = v;
        }
        __syncthreads();
#pragma unroll
        for (int ks = 0; ks < 2; ks++) {
            half8 af[4], bf[4];
#pragma unroll
            for (int r = 0; r < 4; r++)
                af[r] = *(half8*)&Asm[(wy * 64 + r * 16 + m16) * LDK + ks * 32 + quad * 8];
#pragma unroll
            for (int c = 0; c < 4; c++)
                bf[c] = *(half8*)&Bsm[(wx * 64 + c * 16 + m16) * LDK + ks * 32 + quad * 8];
#pragma unroll
            for (int r = 0; r < 4; r++)
#pragma unroll
                for (int c = 0; c < 4; c++)
                    acc[r][c] = __builtin_amdgcn_mfma_f32_16x16x32_f16(af[r], bf[c], acc[r][c], 0, 0, 0);
        }
    }
#pragma unroll
    for (int r = 0; r < 4; r++) {
#pragma unroll
        for (int v = 0; v < 4; v++) {
            int m = wy * 64 + r * 16 + quad * 4 + v;
            int row = row0 + m;
            if (row < nrows) {
#pragma unroll
                for (int c = 0; c < 4; c++) {
                    int n = wx * 64 + c * 16 + m16;
                    float val = acc[r][c][v] + bv[c];
                    if (OMODE == 0) {
                        ((float*)outp)[(size_t)row * HID + n] = val;
                    } else {
                        ((unsigned char*)outp)[(size_t)row * HID + n] = f32_to_fp8(val);
                    }
                }
            }
        }
    }
}

// ------------- LayerNorm + ReLU (layer 0 only), fp8 chunk-major out a8[4][N][32] -------------

__global__ __launch_bounds__(256) void ln_relu_kernel(const float* __restrict__ x,
                                                      const float* __restrict__ g,
                                                      const float* __restrict__ b,
                                                      unsigned char* __restrict__ a8) {
    int row = (blockIdx.x * 256 + threadIdx.x) >> 6;
    int lane = threadIdx.x & 63;
    if (row >= N_NODES) return;
    float2 v = *(const float2*)(x + (size_t)row * HID + 2 * lane);
    float s = v.x + v.y;
#pragma unroll
    for (int off = 1; off < 64; off <<= 1) s += __shfl_xor(s, off);
    float mu = s * (1.0f / 128.0f);
    float d0 = v.x - mu, d1 = v.y - mu;
    float q = d0 * d0 + d1 * d1;
#pragma unroll
    for (int off = 1; off < 64; off <<= 1) q += __shfl_xor(q, off);
    float rstd = rsqrtf(q * (1.0f / 128.0f) + LN_EPS);
    float2 gg = *(const float2*)(g + 2 * lane);
    float2 bb = *(const float2*)(b + 2 * lane);
    float h0 = fmaxf(d0 * rstd * gg.x + bb.x, 0.f);
    float h1 = fmaxf(d1 * rstd * gg.y + bb.y, 0.f);
    int c = lane >> 4;               // (2*lane)/32
    int off2 = (2 * lane) & 31;
    *(unsigned short*)(a8 + (size_t)c * ((size_t)N_NODES * CW) + (size_t)row * CW + off2) =
        pack2_fp8(h0, h1);
}

// ---------- edge aggregation, chunked: pass c gathers from a8[c] (3.2MB, L2-resident) ----------
// 32B rows, 2 lanes/row -> 32 rows per wave-load.

__global__ __launch_bounds__(256) void edge_agg_chunk_kernel(
    const unsigned char* __restrict__ a8, const int* __restrict__ edge_nbr,
    const unsigned* __restrict__ offs, const float* __restrict__ inv_ce,
    _Float16* __restrict__ Ae) {
    int m = blockIdx.x * 4 + (threadIdx.x >> 6);
    int c = blockIdx.y;
    int lane = threadIdx.x & 63;
    int r32 = lane >> 1, t2 = lane & 1;
    unsigned beg = offs[m], end = offs[m + 1];
    float acc[16];
#pragma unroll
    for (int i = 0; i < 16; i++) acc[i] = 0.f;
    const unsigned char* base = a8 + (size_t)c * ((size_t)N_NODES * CW) + t2 * 16;
    unsigned j = beg;
    for (; j + 64 <= end; j += 64) {
        int v0 = __builtin_nontemporal_load(&edge_nbr[j + r32]);
        int v1 = __builtin_nontemporal_load(&edge_nbr[j + 32 + r32]);
        u32x4 w0 = *(const u32x4*)(base + (size_t)v0 * CW);
        u32x4 w1 = *(const u32x4*)(base + (size_t)v1 * CW);
        acc16v(acc, w0);
        acc16v(acc, w1);
    }
    if (j + 32 <= end) {
        int v0 = __builtin_nontemporal_load(&edge_nbr[j + r32]);
        u32x4 w0 = *(const u32x4*)(base + (size_t)v0 * CW);
        acc16v(acc, w0);
        j += 32;
    }
    if (j < end) {
        unsigned idx = j + r32;
        bool val = idx < end;
        int v0 = __builtin_nontemporal_load(&edge_nbr[val ? idx : beg]);
        u32x4 w = *(const u32x4*)(base + (size_t)v0 * CW);
        if (!val) w = (u32x4)0u;
        acc16v(acc, w);
    }
#pragma unroll
    for (int i = 0; i < 16; i++) {
        acc[i] += __shfl_xor(acc[i], 2);
        acc[i] += __shfl_xor(acc[i], 4);
        acc[i] += __shfl_xor(acc[i], 8);
        acc[i] += __shfl_xor(acc[i], 16);
        acc[i] += __shfl_xor(acc[i], 32);
    }
    if (r32 == 0) {
        float ic = inv_ce[m];
        half8 o0, o1;
#pragma unroll
        for (int i = 0; i < 8; i++) o0[i] = (_Float16)(acc[i] * ic);
#pragma unroll
        for (int i = 0; i < 8; i++) o1[i] = (_Float16)(acc[8 + i] * ic);
        _Float16* dst = Ae + (size_t)m * HID + c * CW + t2 * 16;
        __builtin_nontemporal_store(o0, (half8*)dst);
        __builtin_nontemporal_store(o1, (half8*)(dst + 8));
    }
}

// --------- vertex aggregation + residual + fused next-layer LN; Xe8 (2.56MB) L2-resident ---------
// streaming accesses (vert_nbr, x, a8) non-temporal to protect Xe8 residency.

__global__ __launch_bounds__(256) void vert_fused_kernel(
    const unsigned char* __restrict__ Xe8, const unsigned short* __restrict__ vert_nbr,
    const unsigned* __restrict__ offs, const float* __restrict__ inv_cv,
    float* __restrict__ x, const float* __restrict__ gw, const float* __restrict__ bw,
    unsigned char* __restrict__ a8, int do_ln) {
    int v = blockIdx.x * 4 + (threadIdx.x >> 6);
    int lane = threadIdx.x & 63;
    int g = lane >> 3, t = lane & 7;
    unsigned beg = offs[v], end = offs[v + 1];
    float acc[16];
#pragma unroll
    for (int i = 0; i < 16; i++) acc[i] = 0.f;
    const unsigned char* base = Xe8 + t * 16;
    unsigned j = beg;
    for (; j + 16 <= end; j += 16) {
        int e0 = __builtin_nontemporal_load(&vert_nbr[j + g]);
        int e1 = __builtin_nontemporal_load(&vert_nbr[j + 8 + g]);
        u32x4 w0 = *(const u32x4*)(base + (size_t)e0 * HID);
        u32x4 w1 = *(const u32x4*)(base + (size_t)e1 * HID);
        acc16v(acc, w0);
        acc16v(acc, w1);
    }
    if (j + 8 <= end) {
        int e0 = __builtin_nontemporal_load(&vert_nbr[j + g]);
        u32x4 w0 = *(const u32x4*)(base + (size_t)e0 * HID);
        acc16v(acc, w0);
        j += 8;
    }
    if (j < end) {
        unsigned idx = j + g;
        bool val = idx < end;
        int e0 = __builtin_nontemporal_load(&vert_nbr[val ? idx : beg]);
        u32x4 w = *(const u32x4*)(base + (size_t)e0 * HID);
        if (!val) w = (u32x4)0u;
        acc16v(acc, w);
    }
#pragma unroll
    for (int i = 0; i < 16; i++) {
        acc[i] += __shfl_xor(acc[i], 8);
        acc[i] += __shfl_xor(acc[i], 16);
        acc[i] += __shfl_xor(acc[i], 32);
    }
    if (lane < 8) {
        float ic = inv_cv[v];
        float xv[16];
        f32x4* xp = (f32x4*)(x + (size_t)v * HID + t * 16);
        f32x4 xa = __builtin_nontemporal_load(xp);
        f32x4 xb = __builtin_nontemporal_load(xp + 1);
        f32x4 xc = __builtin_nontemporal_load(xp + 2);
        f32x4 xd = __builtin_nontemporal_load(xp + 3);
#pragma unroll
        for (int i = 0; i < 4; i++) { xv[i] = xa[i]; xv[4 + i] = xb[i]; xv[8 + i] = xc[i]; xv[12 + i] = xd[i]; }
#pragma unroll
        for (int i = 0; i < 16; i++) xv[i] += fmaxf(acc[i] * ic, 0.f);
#pragma unroll
        for (int i = 0; i < 4; i++) { xa[i] = xv[i]; xb[i] = xv[4 + i]; xc[i] = xv[8 + i]; xd[i] = xv[12 + i]; }
        __builtin_nontemporal_store(xa, xp);
        __builtin_nontemporal_store(xb, xp + 1);
        __builtin_nontemporal_store(xc, xp + 2);
        __builtin_nontemporal_store(xd, xp + 3);
        if (do_ln) {
            float s = 0.f;
#pragma unroll
            for (int i = 0; i < 16; i++) s += xv[i];
#pragma unroll
            for (int off = 1; off < 8; off <<= 1) s += __shfl_xor(s, off);
            float mu = s * (1.0f / 128.0f);
            float d[16];
            float q = 0.f;
#pragma unroll
            for (int i = 0; i < 16; i++) { d[i] = xv[i] - mu; q += d[i] * d[i]; }
#pragma unroll
            for (int off = 1; off < 8; off <<= 1) q += __shfl_xor(q, off);
            float rstd = rsqrtf(q * (1.0f / 128.0f) + LN_EPS);
            const f32x4* gp = (const f32x4*)(gw + t * 16);
            const f32x4* bp = (const f32x4*)(bw + t * 16);
            float o[16];
#pragma unroll
            for (int k = 0; k < 4; k++) {
                f32x4 gg = gp[k], bb = bp[k];
#pragma unroll
                for (int i = 0; i < 4; i++)
                    o[k * 4 + i] = fmaxf(d[k * 4 + i] * rstd * gg[i] + bb[i], 0.f);
            }
            u32x4 pk;
            pk[0] = pack4_fp8(o[0],  o[1],  o[2],  o[3]);
            pk[1] = pack4_fp8(o[4],  o[5],  o[6],  o[7]);
            pk[2] = pack4_fp8(o[8],  o[9],  o[10], o[11]);
            pk[3] = pack4_fp8(o[12], o[13], o[14], o[15]);
            // chunk-major: byte pos t*16 in row -> chunk t>>1, within-chunk (t&1)*16
            u32x4* dst = (u32x4*)(a8 + (size_t)(t >> 1) * ((size_t)N_NODES * CW) +
                                  (size_t)v * CW + (t & 1) * 16);
            __builtin_nontemporal_store(pk, dst);
        }
    }
}

// ------------------------- head: x @ W_out + b_out, log_softmax -------------------------

__global__ __launch_bounds__(256) void out_kernel(const float* __restrict__ x,
                                                  const float* __restrict__ Wo,
                                                  const float* __restrict__ bo,
                                                  float* __restrict__ out) {
    __shared__ float Ws[128][16];
    __shared__ float rowbuf[16][132];
    __shared__ float bsm[16];
    int tid = threadIdx.x;
#pragma unroll
    for (int i = 0; i < 8; i++) {
        int idx = tid + i * 256;
        ((float*)Ws)[idx] = Wo[idx];
    }
    if (tid < 16) bsm[tid] = bo[tid];
    int row0 = blockIdx.x * 16;
    int w = tid >> 6, lane = tid & 63;
#pragma unroll
    for (int i = 0; i < 8; i++) {
        int idx = lane + i * 64;
        int r = idx >> 7, k = idx & 127;
        int row = row0 + w * 4 + r;
        rowbuf[w * 4 + r][k] = (row < N_NODES) ? x[(size_t)row * HID + k] : 0.f;
    }
    __syncthreads();
    int r = lane >> 4, c = lane & 15;
    int row = row0 + w * 4 + r;
    float acc = bsm[c];
#pragma unroll
    for (int k = 0; k < 128; k++) acc += rowbuf[w * 4 + r][k] * Ws[k][c];
    float mx = acc;
#pragma unroll
    for (int off = 1; off < 16; off <<= 1) mx = fmaxf(mx, __shfl_xor(mx, off));
    float e = expf(acc - mx);
    float s = e;
#pragma unroll
    for (int off = 1; off < 16; off <<= 1) s += __shfl_xor(s, off);
    float val = acc - mx - logf(s);
    if (row < N_NODES) out[(size_t)row * OUT_C + c] = val;
}

// ------------------------- launch -------------------------

extern "C" void kernel_launch(void* const* d_in, const int* in_sizes, int n_in,
                              void* d_out, int out_size, void* d_ws, size_t ws_size,
                              hipStream_t stream) {
    const float* X     = (const float*)d_in[0];
    const int*   v_idx = (const int*)d_in[1];
    const int*   e_idx = (const int*)d_in[2];
    const float* W_enc = (const float*)d_in[3];
    const float* b_enc = (const float*)d_in[4];
    const float* ln_g  = (const float*)d_in[5];
    const float* ln_b  = (const float*)d_in[6];
    const float* Wt    = (const float*)d_in[7];
    const float* bt    = (const float*)d_in[8];
    const float* W_out = (const float*)d_in[9];
    const float* b_out = (const float*)d_in[10];
    float* out = (float*)d_out;

    char* ws = (char*)d_ws;
    auto alloc = [&](size_t bytes) -> void* {
        void* p = (void*)ws;
        ws += (bytes + 255) & ~(size_t)255;
        return p;
    };
    float*    x       = (float*)alloc((size_t)N_NODES * HID * 4);
    unsigned char* a8 = (unsigned char*)alloc((size_t)N_NODES * HID);      // 12.8 MB fp8, [4][N][32]
    _Float16* Ae_h    = (_Float16*)alloc((size_t)M_EDGES * HID * 2);
    unsigned char* Xe8 = (unsigned char*)alloc((size_t)M_EDGES * HID);     // 2.56 MB fp8 (< 4MB L2/XCD)
    _Float16* WencT_h = (_Float16*)alloc((size_t)CIN * HID * 2);
    _Float16* WtT_h   = (_Float16*)alloc((size_t)NLAYERS * HID * HID * 2);
    int* edge_nbr = (int*)alloc((size_t)P_PAIRS * 4);
    unsigned short* vert_nbr = (unsigned short*)alloc((size_t)P_PAIRS * 2);
    unsigned* cnt_e = (unsigned*)alloc((size_t)(M_EDGES + N_NODES) * 4);
    unsigned* cnt_v = cnt_e + M_EDGES;
    unsigned* offs_e = (unsigned*)alloc((size_t)(M_EDGES + 1) * 4);
    unsigned* offs_v = (unsigned*)alloc((size_t)(N_NODES + 1) * 4);
    unsigned* cur_e  = (unsigned*)alloc((size_t)M_EDGES * 4);
    unsigned* cur_v  = (unsigned*)alloc((size_t)N_NODES * 4);
    float* inv_ce = (float*)alloc((size_t)M_EDGES * 4);
    float* inv_cv = (float*)alloc((size_t)N_NODES * 4);
    unsigned* bsum_e = (unsigned*)alloc(64 * 4);
    unsigned* bbase_e = (unsigned*)alloc(64 * 4);
    unsigned* bsum_v = (unsigned*)alloc(64 * 4);
    unsigned* bbase_v = (unsigned*)alloc(64 * 4);

    const int BE = (M_EDGES + SCAN_CHUNK - 1) / SCAN_CHUNK;   // 5
    const int BV = (N_NODES + SCAN_CHUNK - 1) / SCAN_CHUNK;   // 25

    // CSR build
    hipMemsetAsync(cnt_e, 0, (size_t)(M_EDGES + N_NODES) * 4, stream);
    hist_kernel<<<(P_PAIRS + 255) / 256, 256, 0, stream>>>(v_idx, e_idx, cnt_v, cnt_e);
    scan_block_sums<<<BE, 256, 0, stream>>>(cnt_e, M_EDGES, bsum_e);
    scan_tops<<<1, 64, 0, stream>>>(bsum_e, BE, bbase_e, offs_e + M_EDGES);
    scan_final<<<BE, 256, 0, stream>>>(cnt_e, M_EDGES, bbase_e, offs_e, cur_e, inv_ce);
    scan_block_sums<<<BV, 256, 0, stream>>>(cnt_v, N_NODES, bsum_v);
    scan_tops<<<1, 64, 0, stream>>>(bsum_v, BV, bbase_v, offs_v + N_NODES);
    scan_final<<<BV, 256, 0, stream>>>(cnt_v, N_NODES, bbase_v, offs_v, cur_v, inv_cv);
    fill_v_kernel<<<(P_PAIRS + 255) / 256, 256, 0, stream>>>(v_idx, e_idx, cur_v, vert_nbr);
    fill_e_kernel<<<(P_PAIRS + 255) / 256, 256, 0, stream>>>(v_idx, e_idx, cur_e, edge_nbr);

    // weight conversion
    {
        dim3 g1((CIN * HID + 255) / 256, 1);
        convert_wT_kernel<<<g1, 256, 0, stream>>>(W_enc, WencT_h, CIN);
        dim3 g2((HID * HID + 255) / 256, NLAYERS);
        convert_wT_kernel<<<g2, 256, 0, stream>>>(Wt, WtT_h, HID);
    }

    // encoder: x = X @ W_enc + b_enc
    mfma_gemm_kernel<true, 0><<<(N_NODES + 127) / 128, 256, 0, stream>>>(
        (const void*)X, WencT_h, b_enc, (void*)x, N_NODES, CIN);

    // layer-0 LN -> a8 (fp8, chunk-major)
    ln_relu_kernel<<<(N_NODES * 64 + 255) / 256, 256, 0, stream>>>(
        x, ln_g, ln_b, a8);

    // 16 layers
    for (int l = 0; l < NLAYERS; l++) {
        dim3 ge(M_EDGES / 4, NCHUNK);
        edge_agg_chunk_kernel<<<ge, 256, 0, stream>>>(a8, edge_nbr, offs_e, inv_ce, Ae_h);
        mfma_gemm_kernel<false, 1><<<(M_EDGES + 127) / 128, 256, 0, stream>>>(
            (const void*)Ae_h, WtT_h + (size_t)l * HID * HID, bt + l * HID,
            (void*)Xe8, M_EDGES, HID);
        int lnext = (l + 1 < NLAYERS) ? (l + 1) : (NLAYERS - 1);  // pointer kept valid; unused when do_ln=0
        vert_fused_kernel<<<N_NODES / 4, 256, 0, stream>>>(
            Xe8, vert_nbr, offs_v, inv_cv, x,
            ln_g + (size_t)lnext * HID, ln_b + (size_t)lnext * HID, a8,
            (l + 1 < NLAYERS) ? 1 : 0);
    }

    // head
    out_kernel<<<(N_NODES + 15) / 16, 256, 0, stream>>>(x, W_out, b_out, out);
}

// Round 6
// 2211.958 us; speedup vs baseline: 1.5778x; 1.5778x over previous
//
#include <hip/hip_runtime.h>
#include <cstdint>
#include <cstddef>

#define N_NODES 100000
#define M_EDGES 20000
#define P_PAIRS 1600000
#define CIN 768
#define HID 128
#define OUT_C 16
#define NLAYERS 16
#define LN_EPS 1e-5f
#define VBLOCKS 2048     // vert kernel grid; 2048*4 waves * 4 vtx = 32768 vtx per sweep

using half8  = __attribute__((ext_vector_type(8))) _Float16;
using half4v = __attribute__((ext_vector_type(4))) _Float16;
using half2v = __attribute__((ext_vector_type(2))) _Float16;
using f32x4  = __attribute__((ext_vector_type(4))) float;
using f32x2  = __attribute__((ext_vector_type(2))) float;
using u32x2  = __attribute__((ext_vector_type(2))) unsigned int;
using u32x4  = __attribute__((ext_vector_type(4))) unsigned int;

#if defined(__has_builtin)
#if __has_builtin(__builtin_amdgcn_cvt_pk_f32_fp8) && __has_builtin(__builtin_amdgcn_cvt_pk_fp8_f32)
#define HAVE_HW_FP8 1
#endif
#endif

#ifndef HAVE_HW_FP8
#include <hip/hip_fp8.h>
#endif

// ---- fp8 e4m3 helpers ----

__device__ __forceinline__ void acc4w(float* acc, unsigned w) {
#ifdef HAVE_HW_FP8
    f32x2 lo = __builtin_amdgcn_cvt_pk_f32_fp8((int)w, false);
    f32x2 hi = __builtin_amdgcn_cvt_pk_f32_fp8((int)w, true);
    acc[0] += lo[0]; acc[1] += lo[1]; acc[2] += hi[0]; acc[3] += hi[1];
#else
#pragma unroll
    for (int i = 0; i < 4; i++) {
        __half_raw hr = __hip_cvt_fp8_to_halfraw((__hip_fp8_storage_t)((w >> (8 * i)) & 0xffu), __HIP_E4M3);
        acc[i] += __half2float(*(__half*)&hr);
    }
#endif
}

__device__ __forceinline__ void acc16v(float* acc, u32x4 w) {
    acc4w(acc + 0,  w[0]);
    acc4w(acc + 4,  w[1]);
    acc4w(acc + 8,  w[2]);
    acc4w(acc + 12, w[3]);
}

__device__ __forceinline__ unsigned char f32_to_fp8(float v) {
#ifdef HAVE_HW_FP8
    return (unsigned char)(__builtin_amdgcn_cvt_pk_fp8_f32(v, v, 0, false) & 0xff);
#else
    return (unsigned char)__hip_cvt_float_to_fp8(v, __HIP_SATFINITE, __HIP_E4M3);
#endif
}

__device__ __forceinline__ unsigned short pack2_fp8(float a, float b) {
#ifdef HAVE_HW_FP8
    return (unsigned short)(__builtin_amdgcn_cvt_pk_fp8_f32(a, b, 0, false) & 0xffff);
#else
    return (unsigned short)((unsigned)f32_to_fp8(a) | ((unsigned)f32_to_fp8(b) << 8));
#endif
}

__device__ __forceinline__ unsigned pack4_fp8(float a, float b, float c, float d) {
#ifdef HAVE_HW_FP8
    int w = __builtin_amdgcn_cvt_pk_fp8_f32(a, b, 0, false);
    w = __builtin_amdgcn_cvt_pk_fp8_f32(c, d, w, true);
    return (unsigned)w;
#else
    return (unsigned)f32_to_fp8(a) | ((unsigned)f32_to_fp8(b) << 8) |
           ((unsigned)f32_to_fp8(c) << 16) | ((unsigned)f32_to_fp8(d) << 24);
#endif
}

// ------------------------- CSR build -------------------------

__global__ void hist_kernel(const int* __restrict__ v_idx, const int* __restrict__ e_idx,
                            unsigned* __restrict__ cnt_v, unsigned* __restrict__ cnt_e) {
    int p = blockIdx.x * 256 + threadIdx.x;
    if (p < P_PAIRS) {
        atomicAdd(&cnt_v[v_idx[p]], 1u);
        atomicAdd(&cnt_e[e_idx[p]], 1u);
    }
}

// ---- parallel scan: 3 phases ----
#define SCAN_EPT 16
#define SCAN_CHUNK 4096   // 256 threads * 16

__global__ void scan_block_sums(const unsigned* __restrict__ cnt, int n,
                                unsigned* __restrict__ bsum) {
    __shared__ unsigned ws[4];
    int t = threadIdx.x;
    int base = blockIdx.x * SCAN_CHUNK + t * SCAN_EPT;
    unsigned s = 0;
#pragma unroll
    for (int i = 0; i < SCAN_EPT; i++) {
        int idx = base + i;
        if (idx < n) s += cnt[idx];
    }
#pragma unroll
    for (int off = 1; off < 64; off <<= 1) s += __shfl_xor(s, off);
    int lane = t & 63, w = t >> 6;
    if (lane == 0) ws[w] = s;
    __syncthreads();
    if (t == 0) bsum[blockIdx.x] = ws[0] + ws[1] + ws[2] + ws[3];
}

// single wave; B <= 64
__global__ void scan_tops(const unsigned* __restrict__ bsum, int B,
                          unsigned* __restrict__ bbase, unsigned* __restrict__ total_out) {
    int t = threadIdx.x;
    unsigned v = (t < B) ? bsum[t] : 0u;
    unsigned s = v;
#pragma unroll
    for (int off = 1; off < 64; off <<= 1) {
        unsigned u = __shfl_up(s, off);
        if (t >= off) s += u;
    }
    if (t < B) bbase[t] = s - v;
    if (t == 63) *total_out = s;
}

__global__ void scan_final(const unsigned* __restrict__ cnt, int n,
                           const unsigned* __restrict__ bbase,
                           unsigned* __restrict__ offs, unsigned* __restrict__ cur,
                           float* __restrict__ inv) {
    __shared__ unsigned wtot[4];
    int t = threadIdx.x;
    int lane = t & 63, w = t >> 6;
    int base = blockIdx.x * SCAN_CHUNK + t * SCAN_EPT;
    unsigned vals[SCAN_EPT];
    unsigned tsum = 0;
#pragma unroll
    for (int i = 0; i < SCAN_EPT; i++) {
        int idx = base + i;
        unsigned v = (idx < n) ? cnt[idx] : 0u;
        vals[i] = v;
        tsum += v;
    }
    unsigned s = tsum;
#pragma unroll
    for (int off = 1; off < 64; off <<= 1) {
        unsigned u = __shfl_up(s, off);
        if (lane >= off) s += u;
    }
    unsigned texcl = s - tsum;
    if (lane == 63) wtot[w] = s;
    __syncthreads();
    unsigned wbase = 0;
    for (int i = 0; i < w; i++) wbase += wtot[i];
    unsigned run = bbase[blockIdx.x] + wbase + texcl;
#pragma unroll
    for (int i = 0; i < SCAN_EPT; i++) {
        int idx = base + i;
        if (idx < n) {
            offs[idx] = run;
            cur[idx] = run;
            unsigned c = vals[i];
            inv[idx] = 1.0f / (float)(c > 1u ? c : 1u);
            run += c;
        }
    }
}

// ---- fills: separate kernels (merged variant measured pathological: 280us, 6.8GB FETCH) ----

__global__ void fill_v_kernel(const int* __restrict__ v_idx, const int* __restrict__ e_idx,
                              unsigned* __restrict__ cur_v, unsigned short* __restrict__ vert_nbr) {
    int p = blockIdx.x * 256 + threadIdx.x;
    if (p < P_PAIRS) {
        unsigned s = atomicAdd(&cur_v[v_idx[p]], 1u);
        vert_nbr[s] = (unsigned short)e_idx[p];   // e < 20000 fits u16
    }
}

__global__ void fill_e_kernel(const int* __restrict__ v_idx, const int* __restrict__ e_idx,
                              unsigned* __restrict__ cur_e, int* __restrict__ edge_nbr) {
    int p = blockIdx.x * 256 + threadIdx.x;
    if (p < P_PAIRS) {
        unsigned s = atomicAdd(&cur_e[e_idx[p]], 1u);
        edge_nbr[s] = v_idx[p];
    }
}

// ------------------------- weight transpose+convert -------------------------

__global__ void convert_wT_kernel(const float* __restrict__ W, _Float16* __restrict__ WT,
                                  int K) {
    const float* src = W + (size_t)blockIdx.y * K * 128;
    _Float16* dst = WT + (size_t)blockIdx.y * K * 128;
    int idx = blockIdx.x * 256 + threadIdx.x;
    if (idx < K * 128) {
        int k = idx >> 7, n = idx & 127;
        dst[(size_t)n * K + k] = (_Float16)src[idx];
    }
}

// ------------------------- MFMA GEMM -------------------------

#define BK  64
#define LDK 72

// OMODE 0: f32 row-major out (encoder -> x)
// OMODE 1: fp8 row-major out (theta -> Xe8[nrows][128])
template<bool A_FP32, int OMODE>
__global__ __launch_bounds__(256) void mfma_gemm_kernel(
    const void* __restrict__ Ap, const _Float16* __restrict__ Bt,
    const float* __restrict__ bias, void* __restrict__ outp,
    int nrows, int K) {
    __shared__ _Float16 Asm[128 * LDK];
    __shared__ _Float16 Bsm[128 * LDK];
    int tid = threadIdx.x;
    int row0 = blockIdx.x * 128;
    int lane = tid & 63, wave = tid >> 6;
    int wy = wave >> 1, wx = wave & 1;
    int m16 = lane & 15, quad = lane >> 4;

    f32x4 acc[4][4];
#pragma unroll
    for (int r = 0; r < 4; r++)
#pragma unroll
        for (int c = 0; c < 4; c++) acc[r][c] = (f32x4)0.f;

    float bv[4];
#pragma unroll
    for (int c = 0; c < 4; c++) bv[c] = bias[wx * 64 + c * 16 + m16];

    for (int k0 = 0; k0 < K; k0 += BK) {
        __syncthreads();
        if (A_FP32) {
            const float* A = (const float*)Ap;
#pragma unroll
            for (int i = 0; i < 8; i++) {
                int idx = tid + i * 256;
                int r = idx >> 4, c = idx & 15;
                int rg = row0 + r; if (rg >= nrows) rg = nrows - 1;
                float4 v = *(const float4*)(A + (size_t)rg * K + k0 + c * 4);
                half4v h = { (_Float16)v.x, (_Float16)v.y, (_Float16)v.z, (_Float16)v.w };
                *(half4v*)&Asm[r * LDK + c * 4] = h;
            }
        } else {
            const _Float16* A = (const _Float16*)Ap;
#pragma unroll
            for (int i = 0; i < 4; i++) {
                int idx = tid + i * 256;
                int r = idx >> 3, c = idx & 7;
                int rg = row0 + r; if (rg >= nrows) rg = nrows - 1;
                half8 v = *(const half8*)(A + (size_t)rg * K + k0 + c * 8);
                *(half8*)&Asm[r * LDK + c * 8] = v;
            }
        }
#pragma unroll
        for (int i = 0; i < 4; i++) {
            int idx = tid + i * 256;
            int r = idx >> 3, c = idx & 7;
            half8 v = *(const half8*)(Bt + (size_t)r * K + k0 + c * 8);
            *(half8*)&Bsm[r * LDK + c * 8] = v;
        }
        __syncthreads();
#pragma unroll
        for (int ks = 0; ks < 2; ks++) {
            half8 af[4], bf[4];
#pragma unroll
            for (int r = 0; r < 4; r++)
                af[r] = *(half8*)&Asm[(wy * 64 + r * 16 + m16) * LDK + ks * 32 + quad * 8];
#pragma unroll
            for (int c = 0; c < 4; c++)
                bf[c] = *(half8*)&Bsm[(wx * 64 + c * 16 + m16) * LDK + ks * 32 + quad * 8];
#pragma unroll
            for (int r = 0; r < 4; r++)
#pragma unroll
                for (int c = 0; c < 4; c++)
                    acc[r][c] = __builtin_amdgcn_mfma_f32_16x16x32_f16(af[r], bf[c], acc[r][c], 0, 0, 0);
        }
    }
#pragma unroll
    for (int r = 0; r < 4; r++) {
#pragma unroll
        for (int v = 0; v < 4; v++) {
            int m = wy * 64 + r * 16 + quad * 4 + v;
            int row = row0 + m;
            if (row < nrows) {
#pragma unroll
                for (int c = 0; c < 4; c++) {
                    int n = wx * 64 + c * 16 + m16;
                    float val = acc[r][c][v] + bv[c];
                    if (OMODE == 0) {
                        ((float*)outp)[(size_t)row * HID + n] = val;
                    } else {
                        ((unsigned char*)outp)[(size_t)row * HID + n] = f32_to_fp8(val);
                    }
                }
            }
        }
    }
}

// ------------------------- LayerNorm + ReLU (layer 0 only), fp8 row-major out -------------------------

__global__ __launch_bounds__(256) void ln_relu_kernel(const float* __restrict__ x,
                                                      const float* __restrict__ g,
                                                      const float* __restrict__ b,
                                                      unsigned char* __restrict__ a8) {
    int row = (blockIdx.x * 256 + threadIdx.x) >> 6;
    int lane = threadIdx.x & 63;
    if (row >= N_NODES) return;
    float2 v = *(const float2*)(x + (size_t)row * HID + 2 * lane);
    float s = v.x + v.y;
#pragma unroll
    for (int off = 1; off < 64; off <<= 1) s += __shfl_xor(s, off);
    float mu = s * (1.0f / 128.0f);
    float d0 = v.x - mu, d1 = v.y - mu;
    float q = d0 * d0 + d1 * d1;
#pragma unroll
    for (int off = 1; off < 64; off <<= 1) q += __shfl_xor(q, off);
    float rstd = rsqrtf(q * (1.0f / 128.0f) + LN_EPS);
    float2 gg = *(const float2*)(g + 2 * lane);
    float2 bb = *(const float2*)(b + 2 * lane);
    float h0 = fmaxf(d0 * rstd * gg.x + bb.x, 0.f);
    float h1 = fmaxf(d1 * rstd * gg.y + bb.y, 0.f);
    *(unsigned short*)(a8 + (size_t)row * HID + 2 * lane) = pack2_fp8(h0, h1);
}

// ------------------------- edge aggregation: fp8 rows (128B), 8 rows/wave-load -------------------------
// (identical to round-4's kernel: best-measured variant)

__global__ __launch_bounds__(256) void edge_agg_kernel(const unsigned char* __restrict__ a8,
                                                       const int* __restrict__ edge_nbr,
                                                       const unsigned* __restrict__ offs,
                                                       const float* __restrict__ inv_ce,
                                                       _Float16* __restrict__ Ae) {
    int m = blockIdx.x * 4 + (threadIdx.x >> 6);
    int lane = threadIdx.x & 63;
    int g = lane >> 3, t = lane & 7;   // 8 groups of 8 lanes; each lane loads 16B of a 128B row
    unsigned beg = offs[m], end = offs[m + 1];
    float acc[16];
#pragma unroll
    for (int i = 0; i < 16; i++) acc[i] = 0.f;
    const unsigned char* base = a8 + t * 16;
    unsigned j = beg;
    for (; j + 16 <= end; j += 16) {
        int v0 = edge_nbr[j + g];
        int v1 = edge_nbr[j + 8 + g];
        u32x4 w0 = *(const u32x4*)(base + (size_t)v0 * HID);
        u32x4 w1 = *(const u32x4*)(base + (size_t)v1 * HID);
        acc16v(acc, w0);
        acc16v(acc, w1);
    }
    if (j + 8 <= end) {
        int v0 = edge_nbr[j + g];
        u32x4 w0 = *(const u32x4*)(base + (size_t)v0 * HID);
        acc16v(acc, w0);
        j += 8;
    }
    if (j < end) {
        unsigned idx = j + g;
        bool val = idx < end;
        int v0 = edge_nbr[val ? idx : beg];
        u32x4 w = *(const u32x4*)(base + (size_t)v0 * HID);
        if (!val) w = (u32x4)0u;
        acc16v(acc, w);
    }
#pragma unroll
    for (int i = 0; i < 16; i++) {
        acc[i] += __shfl_xor(acc[i], 8);
        acc[i] += __shfl_xor(acc[i], 16);
        acc[i] += __shfl_xor(acc[i], 32);
    }
    if (lane < 8) {
        float ic = inv_ce[m];
        half8 o0, o1;
#pragma unroll
        for (int i = 0; i < 8; i++) o0[i] = (_Float16)(acc[i] * ic);
#pragma unroll
        for (int i = 0; i < 8; i++) o1[i] = (_Float16)(acc[8 + i] * ic);
        *(half8*)(Ae + (size_t)m * HID + t * 16) = o0;
        *(half8*)(Ae + (size_t)m * HID + t * 16 + 8) = o1;
    }
}

// --------- vertex aggregation, COLUMN-OWNERSHIP: 4 vtx/wave, 16 lanes/vtx, no cross-lane reduce ---------
// Each lane owns 8 fp8 columns (bytes t*8..t*8+7); member index loads are uniform within the
// 16-lane group (HW broadcast). Grid-stride over vertices: 2048 blocks total.

__global__ __launch_bounds__(256) void vert_fused_kernel(
    const unsigned char* __restrict__ Xe8, const unsigned short* __restrict__ vert_nbr,
    const unsigned* __restrict__ offs, const float* __restrict__ inv_cv,
    float* __restrict__ x, const float* __restrict__ gw, const float* __restrict__ bw,
    unsigned char* __restrict__ a8, int do_ln) {
    int wave_id = blockIdx.x * 4 + (threadIdx.x >> 6);
    int lane = threadIdx.x & 63;
    int t = lane & 15;                 // column group: owns bytes [t*8, t*8+8)
    const unsigned char* base = Xe8 + t * 8;

    // preload LN params for this lane's columns (uniform across vertices)
    f32x2 g01 = {0.f, 0.f};
    f32x4 gg0, gg1, bb0, bb1;
    if (do_ln) {
        gg0 = *(const f32x4*)(gw + t * 8);
        gg1 = *(const f32x4*)(gw + t * 8 + 4);
        bb0 = *(const f32x4*)(bw + t * 8);
        bb1 = *(const f32x4*)(bw + t * 8 + 4);
    }
    (void)g01;

    for (int v = wave_id * 4 + (lane >> 4); v < N_NODES; v += VBLOCKS * 16) {
        unsigned beg = offs[v], end = offs[v + 1];
        float acc[8] = {0.f, 0.f, 0.f, 0.f, 0.f, 0.f, 0.f, 0.f};
        unsigned j = beg;
        for (; j + 4 <= end; j += 4) {
            int e0 = vert_nbr[j];
            int e1 = vert_nbr[j + 1];
            int e2 = vert_nbr[j + 2];
            int e3 = vert_nbr[j + 3];
            u32x2 w0 = *(const u32x2*)(base + (size_t)e0 * HID);
            u32x2 w1 = *(const u32x2*)(base + (size_t)e1 * HID);
            u32x2 w2 = *(const u32x2*)(base + (size_t)e2 * HID);
            u32x2 w3 = *(const u32x2*)(base + (size_t)e3 * HID);
            acc4w(acc, w0[0]); acc4w(acc + 4, w0[1]);
            acc4w(acc, w1[0]); acc4w(acc + 4, w1[1]);
            acc4w(acc, w2[0]); acc4w(acc + 4, w2[1]);
            acc4w(acc, w3[0]); acc4w(acc + 4, w3[1]);
        }
        for (; j < end; j++) {
            int e0 = vert_nbr[j];
            u32x2 w0 = *(const u32x2*)(base + (size_t)e0 * HID);
            acc4w(acc, w0[0]); acc4w(acc + 4, w0[1]);
        }
        float ic = inv_cv[v];
        float xv[8];
        f32x4* xp = (f32x4*)(x + (size_t)v * HID + t * 8);
        f32x4 xa = xp[0], xb = xp[1];
#pragma unroll
        for (int i = 0; i < 4; i++) { xv[i] = xa[i]; xv[4 + i] = xb[i]; }
#pragma unroll
        for (int i = 0; i < 8; i++) xv[i] += fmaxf(acc[i] * ic, 0.f);
#pragma unroll
        for (int i = 0; i < 4; i++) { xa[i] = xv[i]; xb[i] = xv[4 + i]; }
        xp[0] = xa; xp[1] = xb;
        if (do_ln) {
            float s = 0.f;
#pragma unroll
            for (int i = 0; i < 8; i++) s += xv[i];
#pragma unroll
            for (int off = 1; off < 16; off <<= 1) s += __shfl_xor(s, off);  // group-local (off<16)
            float mu = s * (1.0f / 128.0f);
            float d[8];
            float q = 0.f;
#pragma unroll
            for (int i = 0; i < 8; i++) { d[i] = xv[i] - mu; q += d[i] * d[i]; }
#pragma unroll
            for (int off = 1; off < 16; off <<= 1) q += __shfl_xor(q, off);
            float rstd = rsqrtf(q * (1.0f / 128.0f) + LN_EPS);
            float o[8];
#pragma unroll
            for (int i = 0; i < 4; i++) o[i]     = fmaxf(d[i]     * rstd * gg0[i] + bb0[i], 0.f);
#pragma unroll
            for (int i = 0; i < 4; i++) o[4 + i] = fmaxf(d[4 + i] * rstd * gg1[i] + bb1[i], 0.f);
            u32x2 pk;
            pk[0] = pack4_fp8(o[0], o[1], o[2], o[3]);
            pk[1] = pack4_fp8(o[4], o[5], o[6], o[7]);
            *(u32x2*)(a8 + (size_t)v * HID + t * 8) = pk;
        }
    }
}

// ------------------------- head: x @ W_out + b_out, log_softmax -------------------------

__global__ __launch_bounds__(256) void out_kernel(const float* __restrict__ x,
                                                  const float* __restrict__ Wo,
                                                  const float* __restrict__ bo,
                                                  float* __restrict__ out) {
    __shared__ float Ws[128][16];
    __shared__ float rowbuf[16][132];
    __shared__ float bsm[16];
    int tid = threadIdx.x;
#pragma unroll
    for (int i = 0; i < 8; i++) {
        int idx = tid + i * 256;
        ((float*)Ws)[idx] = Wo[idx];
    }
    if (tid < 16) bsm[tid] = bo[tid];
    int row0 = blockIdx.x * 16;
    int w = tid >> 6, lane = tid & 63;
#pragma unroll
    for (int i = 0; i < 8; i++) {
        int idx = lane + i * 64;
        int r = idx >> 7, k = idx & 127;
        int row = row0 + w * 4 + r;
        rowbuf[w * 4 + r][k] = (row < N_NODES) ? x[(size_t)row * HID + k] : 0.f;
    }
    __syncthreads();
    int r = lane >> 4, c = lane & 15;
    int row = row0 + w * 4 + r;
    float acc = bsm[c];
#pragma unroll
    for (int k = 0; k < 128; k++) acc += rowbuf[w * 4 + r][k] * Ws[k][c];
    float mx = acc;
#pragma unroll
    for (int off = 1; off < 16; off <<= 1) mx = fmaxf(mx, __shfl_xor(mx, off));
    float e = expf(acc - mx);
    float s = e;
#pragma unroll
    for (int off = 1; off < 16; off <<= 1) s += __shfl_xor(s, off);
    float val = acc - mx - logf(s);
    if (row < N_NODES) out[(size_t)row * OUT_C + c] = val;
}

// ------------------------- launch -------------------------

extern "C" void kernel_launch(void* const* d_in, const int* in_sizes, int n_in,
                              void* d_out, int out_size, void* d_ws, size_t ws_size,
                              hipStream_t stream) {
    const float* X     = (const float*)d_in[0];
    const int*   v_idx = (const int*)d_in[1];
    const int*   e_idx = (const int*)d_in[2];
    const float* W_enc = (const float*)d_in[3];
    const float* b_enc = (const float*)d_in[4];
    const float* ln_g  = (const float*)d_in[5];
    const float* ln_b  = (const float*)d_in[6];
    const float* Wt    = (const float*)d_in[7];
    const float* bt    = (const float*)d_in[8];
    const float* W_out = (const float*)d_in[9];
    const float* b_out = (const float*)d_in[10];
    float* out = (float*)d_out;

    char* ws = (char*)d_ws;
    auto alloc = [&](size_t bytes) -> void* {
        void* p = (void*)ws;
        ws += (bytes + 255) & ~(size_t)255;
        return p;
    };
    float*    x       = (float*)alloc((size_t)N_NODES * HID * 4);
    unsigned char* a8 = (unsigned char*)alloc((size_t)N_NODES * HID);      // 12.8 MB fp8
    _Float16* Ae_h    = (_Float16*)alloc((size_t)M_EDGES * HID * 2);
    unsigned char* Xe8 = (unsigned char*)alloc((size_t)M_EDGES * HID);     // 2.56 MB fp8
    _Float16* WencT_h = (_Float16*)alloc((size_t)CIN * HID * 2);
    _Float16* WtT_h   = (_Float16*)alloc((size_t)NLAYERS * HID * HID * 2);
    int* edge_nbr = (int*)alloc((size_t)P_PAIRS * 4);
    unsigned short* vert_nbr = (unsigned short*)alloc((size_t)P_PAIRS * 2);
    unsigned* cnt_e = (unsigned*)alloc((size_t)(M_EDGES + N_NODES) * 4);
    unsigned* cnt_v = cnt_e + M_EDGES;
    unsigned* offs_e = (unsigned*)alloc((size_t)(M_EDGES + 1) * 4);
    unsigned* offs_v = (unsigned*)alloc((size_t)(N_NODES + 1) * 4);
    unsigned* cur_e  = (unsigned*)alloc((size_t)M_EDGES * 4);
    unsigned* cur_v  = (unsigned*)alloc((size_t)N_NODES * 4);
    float* inv_ce = (float*)alloc((size_t)M_EDGES * 4);
    float* inv_cv = (float*)alloc((size_t)N_NODES * 4);
    unsigned* bsum_e = (unsigned*)alloc(64 * 4);
    unsigned* bbase_e = (unsigned*)alloc(64 * 4);
    unsigned* bsum_v = (unsigned*)alloc(64 * 4);
    unsigned* bbase_v = (unsigned*)alloc(64 * 4);

    const int BE = (M_EDGES + SCAN_CHUNK - 1) / SCAN_CHUNK;   // 5
    const int BV = (N_NODES + SCAN_CHUNK - 1) / SCAN_CHUNK;   // 25

    // CSR build
    hipMemsetAsync(cnt_e, 0, (size_t)(M_EDGES + N_NODES) * 4, stream);
    hist_kernel<<<(P_PAIRS + 255) / 256, 256, 0, stream>>>(v_idx, e_idx, cnt_v, cnt_e);
    scan_block_sums<<<BE, 256, 0, stream>>>(cnt_e, M_EDGES, bsum_e);
    scan_tops<<<1, 64, 0, stream>>>(bsum_e, BE, bbase_e, offs_e + M_EDGES);
    scan_final<<<BE, 256, 0, stream>>>(cnt_e, M_EDGES, bbase_e, offs_e, cur_e, inv_ce);
    scan_block_sums<<<BV, 256, 0, stream>>>(cnt_v, N_NODES, bsum_v);
    scan_tops<<<1, 64, 0, stream>>>(bsum_v, BV, bbase_v, offs_v + N_NODES);
    scan_final<<<BV, 256, 0, stream>>>(cnt_v, N_NODES, bbase_v, offs_v, cur_v, inv_cv);
    fill_v_kernel<<<(P_PAIRS + 255) / 256, 256, 0, stream>>>(v_idx, e_idx, cur_v, vert_nbr);
    fill_e_kernel<<<(P_PAIRS + 255) / 256, 256, 0, stream>>>(v_idx, e_idx, cur_e, edge_nbr);

    // weight conversion
    {
        dim3 g1((CIN * HID + 255) / 256, 1);
        convert_wT_kernel<<<g1, 256, 0, stream>>>(W_enc, WencT_h, CIN);
        dim3 g2((HID * HID + 255) / 256, NLAYERS);
        convert_wT_kernel<<<g2, 256, 0, stream>>>(Wt, WtT_h, HID);
    }

    // encoder: x = X @ W_enc + b_enc
    mfma_gemm_kernel<true, 0><<<(N_NODES + 127) / 128, 256, 0, stream>>>(
        (const void*)X, WencT_h, b_enc, (void*)x, N_NODES, CIN);

    // layer-0 LN -> a8 (fp8, row-major)
    ln_relu_kernel<<<(N_NODES * 64 + 255) / 256, 256, 0, stream>>>(
        x, ln_g, ln_b, a8);

    // 16 layers
    for (int l = 0; l < NLAYERS; l++) {
        edge_agg_kernel<<<M_EDGES / 4, 256, 0, stream>>>(a8, edge_nbr, offs_e, inv_ce, Ae_h);
        mfma_gemm_kernel<false, 1><<<(M_EDGES + 127) / 128, 256, 0, stream>>>(
            (const void*)Ae_h, WtT_h + (size_t)l * HID * HID, bt + l * HID,
            (void*)Xe8, M_EDGES, HID);
        int lnext = (l + 1 < NLAYERS) ? (l + 1) : (NLAYERS - 1);  // pointer kept valid; unused when do_ln=0
        vert_fused_kernel<<<VBLOCKS, 256, 0, stream>>>(
            Xe8, vert_nbr, offs_v, inv_cv, x,
            ln_g + (size_t)lnext * HID, ln_b + (size_t)lnext * HID, a8,
            (l + 1 < NLAYERS) ? 1 : 0);
    }

    // head
    out_kernel<<<(N_NODES + 15) / 16, 256, 0, stream>>>(x, W_out, b_out, out);
}